// Round 8
// baseline (188.807 us; speedup 1.0000x reference)
//
#include <hip/hip_runtime.h>
#include <hip/hip_bf16.h>

#define CH 64
#define RPB 128      // rows per bucket
#define RPB_SH 7
#define NBLK 256     // count/fill chunk count
#define MAXNB 800    // max buckets supported by LDS arrays
#define SCAN_B 512
#define CAP 4608     // max records per bucket for in-LDS sort (mean 4096 + 8 sigma)
#define GEMM_BLOCKS 1024

typedef __attribute__((ext_vector_type(8))) short short8;
typedef __attribute__((ext_vector_type(4))) float f32x4;

__device__ __forceinline__ unsigned short f2bf(float f) {
  unsigned int u = __float_as_uint(f);
  u = u + 0x7FFFu + ((u >> 16) & 1u);  // RNE
  return (unsigned short)(u >> 16);
}
__device__ __forceinline__ float bf2f(unsigned short s) {
  return __uint_as_float(((unsigned int)s) << 16);
}

// ---------------------------------------------------------------------------
// Kernel 1 (merged): blocks [0, GEMM_BLOCKS) run the fused dual GEMM (MFMA,
// split-bf16). Blocks [GEMM_BLOCKS, GEMM_BLOCKS+NBLK) run countT (per-bucket
// LDS histogram). Independent work — countT hides under the GEMM.
// ---------------------------------------------------------------------------
__global__ __launch_bounds__(256) void gemm_count_kernel(
    const float* __restrict__ x, const float* __restrict__ wc,
    const float* __restrict__ wl, unsigned short* __restrict__ xwb,
    float* __restrict__ out, int n,
    const int* __restrict__ r1, const int* __restrict__ r2,
    int* __restrict__ countsT, int nnz, int nb) {
  __shared__ int h[MAXNB];

  if (blockIdx.x >= GEMM_BLOCKS) {
    // ---- countT path ----
    const int blk = blockIdx.x - GEMM_BLOCKS;
    for (int i = threadIdx.x; i < nb; i += 256) h[i] = 0;
    __syncthreads();
    const int tot = 2 * nnz;
    const int chunk = (tot + NBLK - 1) / NBLK;
    const int e0 = blk * chunk;
    const int e1 = min(tot, e0 + chunk);
    for (int e = e0 + threadIdx.x; e < e1; e += 256) {
      const int r = (e < nnz) ? r1[e] : r2[e - nnz];
      atomicAdd(&h[r >> RPB_SH], 1);
    }
    __syncthreads();
    for (int b = threadIdx.x; b < nb; b += 256)
      countsT[b * NBLK + blk] = h[b];
    return;
  }

  // ---- GEMM path ----
  const int lane = threadIdx.x & 63;
  const int wv = threadIdx.x >> 6;
  const int mat = wv >> 1;   // 0: conv, 1: lin
  const int tile = wv & 1;   // row-tile within 32-row group
  const float* __restrict__ W = mat ? wl : wc;

  const int i16 = lane & 15;
  const int kseg = lane >> 4;

  short8 bhi[4][2], blo[4][2];
#pragma unroll
  for (int nt = 0; nt < 4; ++nt)
#pragma unroll
    for (int kk = 0; kk < 2; ++kk)
#pragma unroll
      for (int j = 0; j < 8; ++j) {
        const float w = W[(kk * 32 + kseg * 8 + j) * CH + nt * 16 + i16];
        const unsigned short hh = f2bf(w);
        bhi[nt][kk][j] = (short)hh;
        blo[nt][kk][j] = (short)f2bf(w - bf2f(hh));
      }

  const int ngroups = (n + 31) >> 5;
  for (int g = blockIdx.x; g < ngroups; g += GEMM_BLOCKS) {
    const int base = g * 32 + tile * 16;
    const int row = base + i16;
    const int rowc = (row < n) ? row : (n - 1);
    const float* xp = x + (size_t)rowc * CH + kseg * 8;

    float af[16];
    {
      const float4 p0 = *(const float4*)(xp);
      const float4 p1 = *(const float4*)(xp + 4);
      const float4 q0 = *(const float4*)(xp + 32);
      const float4 q1 = *(const float4*)(xp + 36);
      af[0] = p0.x; af[1] = p0.y; af[2] = p0.z; af[3] = p0.w;
      af[4] = p1.x; af[5] = p1.y; af[6] = p1.z; af[7] = p1.w;
      af[8] = q0.x; af[9] = q0.y; af[10] = q0.z; af[11] = q0.w;
      af[12] = q1.x; af[13] = q1.y; af[14] = q1.z; af[15] = q1.w;
    }
    short8 ahi[2], alo[2];
#pragma unroll
    for (int kk = 0; kk < 2; ++kk)
#pragma unroll
      for (int j = 0; j < 8; ++j) {
        const float f = af[kk * 8 + j];
        const unsigned short hh = f2bf(f);
        ahi[kk][j] = (short)hh;
        alo[kk][j] = (short)f2bf(f - bf2f(hh));
      }

    f32x4 acc[4];
#pragma unroll
    for (int nt = 0; nt < 4; ++nt) {
      f32x4 a = {0.f, 0.f, 0.f, 0.f};
#pragma unroll
      for (int kk = 0; kk < 2; ++kk) {
        a = __builtin_amdgcn_mfma_f32_16x16x32_bf16(ahi[kk], bhi[nt][kk], a, 0, 0, 0);
        a = __builtin_amdgcn_mfma_f32_16x16x32_bf16(alo[kk], bhi[nt][kk], a, 0, 0, 0);
        a = __builtin_amdgcn_mfma_f32_16x16x32_bf16(ahi[kk], blo[nt][kk], a, 0, 0, 0);
      }
      acc[nt] = a;
    }

    if (mat == 0) {
#pragma unroll
      for (int nt = 0; nt < 4; ++nt)
#pragma unroll
        for (int r = 0; r < 4; ++r) {
          const int orow = base + kseg * 4 + r;
          if (orow < n)
            xwb[(size_t)orow * CH + nt * 16 + i16] = f2bf(acc[nt][r]);
        }
    } else {
#pragma unroll
      for (int nt = 0; nt < 4; ++nt)
#pragma unroll
        for (int r = 0; r < 4; ++r) {
          const int orow = base + kseg * 4 + r;
          if (orow < n)
            out[(size_t)orow * CH + nt * 16 + i16] = acc[nt][r];
        }
    }
  }
}

// ---------------------------------------------------------------------------
// Phase B: exclusive scan of countsT (length nb*NBLK), in place, 3 kernels.
// ---------------------------------------------------------------------------
__global__ __launch_bounds__(SCAN_B) void scan_partial(
    const int* __restrict__ in, int* __restrict__ partials, int n) {
  __shared__ int s[SCAN_B];
  const int i = blockIdx.x * SCAN_B + threadIdx.x;
  s[threadIdx.x] = (i < n) ? in[i] : 0;
  __syncthreads();
  for (int off = SCAN_B / 2; off > 0; off >>= 1) {
    if (threadIdx.x < off) s[threadIdx.x] += s[threadIdx.x + off];
    __syncthreads();
  }
  if (threadIdx.x == 0) partials[blockIdx.x] = s[0];
}

__global__ __launch_bounds__(1024) void scan_partials_scan(
    int* __restrict__ partials, int nb) {
  __shared__ int s[1024];
  const int v = (threadIdx.x < nb) ? partials[threadIdx.x] : 0;
  s[threadIdx.x] = v;
  __syncthreads();
  for (int off = 1; off < 1024; off <<= 1) {
    const int t = (threadIdx.x >= off) ? s[threadIdx.x - off] : 0;
    __syncthreads();
    s[threadIdx.x] += t;
    __syncthreads();
  }
  if (threadIdx.x < nb) partials[threadIdx.x] = s[threadIdx.x] - v;  // exclusive
}

__global__ __launch_bounds__(SCAN_B) void scan_final(
    int* __restrict__ data, const int* __restrict__ partials, int n) {
  __shared__ int s[SCAN_B];
  const int i = blockIdx.x * SCAN_B + threadIdx.x;
  const int v = (i < n) ? data[i] : 0;
  s[threadIdx.x] = v;
  __syncthreads();
  for (int off = 1; off < SCAN_B; off <<= 1) {
    const int t = (threadIdx.x >= off) ? s[threadIdx.x - off] : 0;
    __syncthreads();
    s[threadIdx.x] += t;
    __syncthreads();
  }
  if (i < n) data[i] = s[threadIdx.x] - v + partials[blockIdx.x];  // exclusive
}

// ---------------------------------------------------------------------------
// Phase C: fill bucketed edge records. LDS cursors only. 1024 thr (16 waves).
// record.x = ((row & 127) << 17) | col,  record.y = val bits
// ---------------------------------------------------------------------------
__global__ __launch_bounds__(1024) void fillB_kernel(
    const int* __restrict__ r1, const int* __restrict__ c1, const float* __restrict__ v1,
    const int* __restrict__ r2, const int* __restrict__ c2, const float* __restrict__ v2,
    const int* __restrict__ soff, int2* __restrict__ ebuf, int nnz, int nb) {
  __shared__ int cur[MAXNB];
  for (int b = threadIdx.x; b < nb; b += 1024)
    cur[b] = soff[b * NBLK + blockIdx.x];
  __syncthreads();
  const int tot = 2 * nnz;
  const int chunk = (tot + NBLK - 1) / NBLK;
  const int e0 = blockIdx.x * chunk;
  const int e1 = min(tot, e0 + chunk);
  for (int e = e0 + threadIdx.x; e < e1; e += 1024) {
    int r, c;
    float v;
    if (e < nnz) {
      r = r1[e]; c = c1[e]; v = v1[e];
    } else {
      r = r2[e - nnz]; c = c2[e - nnz]; v = v2[e - nnz];
    }
    const int b = r >> RPB_SH;
    const int slot = atomicAdd(&cur[b], 1);
    ebuf[slot] = make_int2(((r & (RPB - 1)) << 17) | c, __float_as_int(v));
  }
}

// ---------------------------------------------------------------------------
// Phase D+E fused: one block per bucket. Sort the bucket's records by local
// row in LDS (counting sort), write the sorted run back in place (L2-hot),
// then the block's 8 waves gather 16 rows each with register accumulation
// and fused sigmoid. Row offsets stay in LDS — no global row_ptr/bflag.
// ---------------------------------------------------------------------------
__global__ __launch_bounds__(512, 8) void sortgather_kernel(
    const int* __restrict__ soff, int2* __restrict__ ebuf,
    const unsigned int* __restrict__ xw32, float2* __restrict__ out2,
    int n, int nb, int tot) {
  __shared__ int2 raw[CAP];   // 36 KB
  __shared__ int hist[RPB];
  __shared__ int incl[RPB];
  __shared__ int cur[RPB];

  const int tid = threadIdx.x;
  const int b = blockIdx.x;
  const int beg = soff[b * NBLK];
  const int end = (b + 1 < nb) ? soff[(b + 1) * NBLK] : tot;
  const int cnt = end - beg;
  const bool sorted = (cnt <= CAP);

  if (sorted) {
    if (tid < RPB) hist[tid] = 0;
    __syncthreads();
    for (int i = tid; i < cnt; i += 512) {
      const int2 rec = ebuf[beg + i];
      raw[i] = rec;
      atomicAdd(&hist[rec.x >> 17], 1);
    }
    __syncthreads();
    // inclusive scan of hist[128] on first 128 threads
    int v = 0;
    if (tid < RPB) {
      v = hist[tid];
      incl[tid] = v;
    }
    __syncthreads();
    for (int off = 1; off < RPB; off <<= 1) {
      int t = 0;
      if (tid < RPB && tid >= off) t = incl[tid - off];
      __syncthreads();
      if (tid < RPB) incl[tid] += t;
      __syncthreads();
    }
    if (tid < RPB) cur[tid] = incl[tid] - v;  // exclusive
    __syncthreads();
    for (int i = tid; i < cnt; i += 512) {
      const int2 rec = raw[i];
      const int pos = atomicAdd(&cur[rec.x >> 17], 1);
      ebuf[beg + pos] = rec;
    }
    __threadfence_block();
    __syncthreads();
  }

  // ---- gather phase: 8 waves x 16 rows ----
  const int lane = tid & 63;
  const int half = lane >> 5;
  const int l32 = lane & 31;
  const int wv = tid >> 6;

  for (int rl = wv; rl < RPB; rl += 8) {
    const int row = b * RPB + rl;
    if (row >= n) continue;

    float2 acc;
    if (half == 0) acc = out2[(size_t)row * 32 + l32];  // linear term
    else acc = make_float2(0.f, 0.f);

    if (sorted) {
      const int rend = beg + incl[rl];
      int e = rend - hist[rl];
      for (; e + 16 <= rend; e += 16) {
        int2 rc[8];
        unsigned int u[8];
#pragma unroll
        for (int j = 0; j < 8; ++j) rc[j] = ebuf[e + 2 * j + half];
#pragma unroll
        for (int j = 0; j < 8; ++j)
          u[j] = xw32[(size_t)(rc[j].x & 0x1FFFF) * 32 + l32];
#pragma unroll
        for (int j = 0; j < 8; ++j) {
          const float v = __int_as_float(rc[j].y);
          acc.x = fmaf(v, __uint_as_float(u[j] << 16), acc.x);
          acc.y = fmaf(v, __uint_as_float(u[j] & 0xFFFF0000u), acc.y);
        }
      }
      for (; e < rend; e += 2) {
        const int idx = e + half;
        const bool ok = idx < rend;
        const int2 rc = ebuf[ok ? idx : (rend - 1)];
        const unsigned int u = xw32[(size_t)(rc.x & 0x1FFFF) * 32 + l32];
        const float v = ok ? __int_as_float(rc.y) : 0.f;
        acc.x = fmaf(v, __uint_as_float(u << 16), acc.x);
        acc.y = fmaf(v, __uint_as_float(u & 0xFFFF0000u), acc.y);
      }
    } else {  // degenerate oversized bucket: predicated scan, half 0 only
      for (int e = beg; e < end; ++e) {
        const int2 rec = ebuf[e];
        if ((rec.x >> 17) == rl && half == 0) {
          const unsigned int u = xw32[(size_t)(rec.x & 0x1FFFF) * 32 + l32];
          const float v = __int_as_float(rec.y);
          acc.x = fmaf(v, __uint_as_float(u << 16), acc.x);
          acc.y = fmaf(v, __uint_as_float(u & 0xFFFF0000u), acc.y);
        }
      }
    }

    acc.x += __shfl_xor(acc.x, 32, 64);
    acc.y += __shfl_xor(acc.y, 32, 64);
    if (half == 0) {
      acc.x = 1.f / (1.f + __expf(-acc.x));
      acc.y = 1.f / (1.f + __expf(-acc.y));
      out2[(size_t)row * 32 + l32] = acc;
    }
  }
}

// ---------------------------------------------------------------------------
// Fallback path (ws too small): atomic scatter + sigmoid.
// ---------------------------------------------------------------------------
__global__ __launch_bounds__(256) void scatter_kernel(
    const int* __restrict__ rows, const int* __restrict__ cols,
    const float* __restrict__ vals, const unsigned short* __restrict__ xwb,
    float* __restrict__ out, int nnz) {
  const int lane = threadIdx.x & 63;
  const int wid = (blockIdx.x * blockDim.x + threadIdx.x) >> 6;
  const int nwaves = (gridDim.x * blockDim.x) >> 6;
  for (int k = wid; k < nnz; k += nwaves) {
    const float xv = bf2f(xwb[(size_t)cols[k] * CH + lane]);
    atomicAdd(&out[(size_t)rows[k] * CH + lane], vals[k] * xv);
  }
}

__global__ __launch_bounds__(256) void sigmoid_kernel(float* __restrict__ out, int n4) {
  const int i = blockIdx.x * blockDim.x + threadIdx.x;
  if (i < n4) {
    float4 v = reinterpret_cast<float4*>(out)[i];
    v.x = 1.f / (1.f + __expf(-v.x));
    v.y = 1.f / (1.f + __expf(-v.y));
    v.z = 1.f / (1.f + __expf(-v.z));
    v.w = 1.f / (1.f + __expf(-v.w));
    reinterpret_cast<float4*>(out)[i] = v;
  }
}

extern "C" void kernel_launch(void* const* d_in, const int* in_sizes, int n_in,
                              void* d_out, int out_size, void* d_ws, size_t ws_size,
                              hipStream_t stream) {
  const float* x         = (const float*)d_in[0];
  const int*   down_rows = (const int*)d_in[1];
  const int*   down_cols = (const int*)d_in[2];
  const float* down_vals = (const float*)d_in[3];
  const int*   up_rows   = (const int*)d_in[4];
  const int*   up_cols   = (const int*)d_in[5];
  const float* up_vals   = (const float*)d_in[6];
  const float* w_conv    = (const float*)d_in[7];
  const float* w_lin     = (const float*)d_in[8];

  const int n   = in_sizes[0] / CH;  // 100000
  const int nnz = in_sizes[1];       // 1600000
  const int tot = 2 * nnz;
  const int nb  = (n + RPB - 1) / RPB;  // 782

  float* out = (float*)d_out;

  // ws layout (xw stored as bf16)
  char* p = (char*)d_ws;
  unsigned short* xwb = (unsigned short*)p;  p += (size_t)n * CH * 2;
  int* soff    = (int*)p;  p += (size_t)nb * NBLK * 4;
  int* partial = (int*)p;  p += 1024 * 4;
  p = (char*)(((uintptr_t)p + 7) & ~(uintptr_t)7);
  int2* ebuf   = (int2*)p; p += (size_t)tot * 8;
  const size_t need = (size_t)(p - (char*)d_ws);

  if (ws_size >= need && nb <= MAXNB && n < (1 << 17)) {
    // GEMM (blocks 0..1023) + countT (blocks 1024..1279) in one launch
    gemm_count_kernel<<<GEMM_BLOCKS + NBLK, 256, 0, stream>>>(
        x, w_conv, w_lin, xwb, out, n, down_rows, up_rows, soff, nnz, nb);
    const int ntot = nb * NBLK;
    const int nsb = (ntot + SCAN_B - 1) / SCAN_B;  // 391 <= 1024
    scan_partial<<<nsb, SCAN_B, 0, stream>>>(soff, partial, ntot);
    scan_partials_scan<<<1, 1024, 0, stream>>>(partial, nsb);
    scan_final<<<nsb, SCAN_B, 0, stream>>>(soff, partial, ntot);
    fillB_kernel<<<NBLK, 1024, 0, stream>>>(down_rows, down_cols, down_vals,
                                            up_rows, up_cols, up_vals,
                                            soff, ebuf, nnz, nb);
    sortgather_kernel<<<nb, 512, 0, stream>>>(soff, ebuf,
                                              (const unsigned int*)xwb,
                                              (float2*)out, n, nb, tot);
  } else {
    // fallback: gemm only (nb=0 disables count work; countsT ptr unused)
    gemm_count_kernel<<<GEMM_BLOCKS, 256, 0, stream>>>(
        x, w_conv, w_lin, xwb, out, n, down_rows, up_rows, (int*)d_ws, nnz, 0);
    scatter_kernel<<<4096, 256, 0, stream>>>(down_rows, down_cols, down_vals, xwb, out, nnz);
    scatter_kernel<<<4096, 256, 0, stream>>>(up_rows, up_cols, up_vals, xwb, out, nnz);
    const int n4 = (n * CH) / 4;
    sigmoid_kernel<<<(n4 + 255) / 256, 256, 0, stream>>>(out, n4);
  }
}

// Round 9
// 157.689 us; speedup vs baseline: 1.1973x; 1.1973x over previous
//
#include <hip/hip_runtime.h>
#include <hip/hip_bf16.h>

#define CH 64
#define RPB 128      // rows per bucket
#define RPB_SH 7
#define NBLK 256     // count/fill chunk count
#define MAXNB 800    // max buckets supported by LDS arrays
#define SCAN_B 512
#define CAP 4608     // max records per bucket for in-LDS sort (mean 4096 + 8 sigma)
#define GEMM_BLOCKS 1024

typedef __attribute__((ext_vector_type(8))) short short8;
typedef __attribute__((ext_vector_type(4))) float f32x4;

__device__ __forceinline__ unsigned short f2bf(float f) {
  unsigned int u = __float_as_uint(f);
  u = u + 0x7FFFu + ((u >> 16) & 1u);  // RNE
  return (unsigned short)(u >> 16);
}
__device__ __forceinline__ float bf2f(unsigned short s) {
  return __uint_as_float(((unsigned int)s) << 16);
}
__device__ __forceinline__ float bflo(unsigned int u) {
  return __uint_as_float(u << 16);
}
__device__ __forceinline__ float bfhi(unsigned int u) {
  return __uint_as_float(u & 0xFFFF0000u);
}

// record encoding: rec.x = (local_row << 24) | (col << 7)   [col*128 = row byte offset]
//                  rec.y = fp32 val bits
#define COLOFF_MASK 0x00FFFF80

// ---------------------------------------------------------------------------
// Kernel 1 (merged): blocks [0, GEMM_BLOCKS) run the fused dual GEMM (MFMA,
// split-bf16). Blocks [GEMM_BLOCKS, GEMM_BLOCKS+NBLK) run countT (per-bucket
// LDS histogram). Independent work — countT hides under the GEMM.
// ---------------------------------------------------------------------------
__global__ __launch_bounds__(256) void gemm_count_kernel(
    const float* __restrict__ x, const float* __restrict__ wc,
    const float* __restrict__ wl, unsigned short* __restrict__ xwb,
    float* __restrict__ out, int n,
    const int* __restrict__ r1, const int* __restrict__ r2,
    int* __restrict__ countsT, int nnz, int nb) {
  __shared__ int h[MAXNB];

  if (blockIdx.x >= GEMM_BLOCKS) {
    // ---- countT path ----
    const int blk = blockIdx.x - GEMM_BLOCKS;
    for (int i = threadIdx.x; i < nb; i += 256) h[i] = 0;
    __syncthreads();
    const int tot = 2 * nnz;
    const int chunk = (tot + NBLK - 1) / NBLK;
    const int e0 = blk * chunk;
    const int e1 = min(tot, e0 + chunk);
    for (int e = e0 + threadIdx.x; e < e1; e += 256) {
      const int r = (e < nnz) ? r1[e] : r2[e - nnz];
      atomicAdd(&h[r >> RPB_SH], 1);
    }
    __syncthreads();
    for (int b = threadIdx.x; b < nb; b += 256)
      countsT[b * NBLK + blk] = h[b];
    return;
  }

  // ---- GEMM path ----
  const int lane = threadIdx.x & 63;
  const int wv = threadIdx.x >> 6;
  const int mat = wv >> 1;   // 0: conv, 1: lin
  const int tile = wv & 1;   // row-tile within 32-row group
  const float* __restrict__ W = mat ? wl : wc;

  const int i16 = lane & 15;
  const int kseg = lane >> 4;

  short8 bhi[4][2], blo[4][2];
#pragma unroll
  for (int nt = 0; nt < 4; ++nt)
#pragma unroll
    for (int kk = 0; kk < 2; ++kk)
#pragma unroll
      for (int j = 0; j < 8; ++j) {
        const float w = W[(kk * 32 + kseg * 8 + j) * CH + nt * 16 + i16];
        const unsigned short hh = f2bf(w);
        bhi[nt][kk][j] = (short)hh;
        blo[nt][kk][j] = (short)f2bf(w - bf2f(hh));
      }

  const int ngroups = (n + 31) >> 5;
  for (int g = blockIdx.x; g < ngroups; g += GEMM_BLOCKS) {
    const int base = g * 32 + tile * 16;
    const int row = base + i16;
    const int rowc = (row < n) ? row : (n - 1);
    const float* xp = x + (size_t)rowc * CH + kseg * 8;

    float af[16];
    {
      const float4 p0 = *(const float4*)(xp);
      const float4 p1 = *(const float4*)(xp + 4);
      const float4 q0 = *(const float4*)(xp + 32);
      const float4 q1 = *(const float4*)(xp + 36);
      af[0] = p0.x; af[1] = p0.y; af[2] = p0.z; af[3] = p0.w;
      af[4] = p1.x; af[5] = p1.y; af[6] = p1.z; af[7] = p1.w;
      af[8] = q0.x; af[9] = q0.y; af[10] = q0.z; af[11] = q0.w;
      af[12] = q1.x; af[13] = q1.y; af[14] = q1.z; af[15] = q1.w;
    }
    short8 ahi[2], alo[2];
#pragma unroll
    for (int kk = 0; kk < 2; ++kk)
#pragma unroll
      for (int j = 0; j < 8; ++j) {
        const float f = af[kk * 8 + j];
        const unsigned short hh = f2bf(f);
        ahi[kk][j] = (short)hh;
        alo[kk][j] = (short)f2bf(f - bf2f(hh));
      }

    f32x4 acc[4];
#pragma unroll
    for (int nt = 0; nt < 4; ++nt) {
      f32x4 a = {0.f, 0.f, 0.f, 0.f};
#pragma unroll
      for (int kk = 0; kk < 2; ++kk) {
        a = __builtin_amdgcn_mfma_f32_16x16x32_bf16(ahi[kk], bhi[nt][kk], a, 0, 0, 0);
        a = __builtin_amdgcn_mfma_f32_16x16x32_bf16(alo[kk], bhi[nt][kk], a, 0, 0, 0);
        a = __builtin_amdgcn_mfma_f32_16x16x32_bf16(ahi[kk], blo[nt][kk], a, 0, 0, 0);
      }
      acc[nt] = a;
    }

    if (mat == 0) {
#pragma unroll
      for (int nt = 0; nt < 4; ++nt)
#pragma unroll
        for (int r = 0; r < 4; ++r) {
          const int orow = base + kseg * 4 + r;
          if (orow < n)
            xwb[(size_t)orow * CH + nt * 16 + i16] = f2bf(acc[nt][r]);
        }
    } else {
#pragma unroll
      for (int nt = 0; nt < 4; ++nt)
#pragma unroll
        for (int r = 0; r < 4; ++r) {
          const int orow = base + kseg * 4 + r;
          if (orow < n)
            out[(size_t)orow * CH + nt * 16 + i16] = acc[nt][r];
        }
    }
  }
}

// ---------------------------------------------------------------------------
// Phase B: exclusive scan of countsT (length nb*NBLK), in place, 3 kernels.
// ---------------------------------------------------------------------------
__global__ __launch_bounds__(SCAN_B) void scan_partial(
    const int* __restrict__ in, int* __restrict__ partials, int n) {
  __shared__ int s[SCAN_B];
  const int i = blockIdx.x * SCAN_B + threadIdx.x;
  s[threadIdx.x] = (i < n) ? in[i] : 0;
  __syncthreads();
  for (int off = SCAN_B / 2; off > 0; off >>= 1) {
    if (threadIdx.x < off) s[threadIdx.x] += s[threadIdx.x + off];
    __syncthreads();
  }
  if (threadIdx.x == 0) partials[blockIdx.x] = s[0];
}

__global__ __launch_bounds__(1024) void scan_partials_scan(
    int* __restrict__ partials, int nb) {
  __shared__ int s[1024];
  const int v = (threadIdx.x < nb) ? partials[threadIdx.x] : 0;
  s[threadIdx.x] = v;
  __syncthreads();
  for (int off = 1; off < 1024; off <<= 1) {
    const int t = (threadIdx.x >= off) ? s[threadIdx.x - off] : 0;
    __syncthreads();
    s[threadIdx.x] += t;
    __syncthreads();
  }
  if (threadIdx.x < nb) partials[threadIdx.x] = s[threadIdx.x] - v;  // exclusive
}

__global__ __launch_bounds__(SCAN_B) void scan_final(
    int* __restrict__ data, const int* __restrict__ partials, int n) {
  __shared__ int s[SCAN_B];
  const int i = blockIdx.x * SCAN_B + threadIdx.x;
  const int v = (i < n) ? data[i] : 0;
  s[threadIdx.x] = v;
  __syncthreads();
  for (int off = 1; off < SCAN_B; off <<= 1) {
    const int t = (threadIdx.x >= off) ? s[threadIdx.x - off] : 0;
    __syncthreads();
    s[threadIdx.x] += t;
    __syncthreads();
  }
  if (i < n) data[i] = s[threadIdx.x] - v + partials[blockIdx.x];  // exclusive
}

// ---------------------------------------------------------------------------
// Phase C: fill bucketed edge records. LDS cursors only. 1024 thr (16 waves).
// ---------------------------------------------------------------------------
__global__ __launch_bounds__(1024) void fillB_kernel(
    const int* __restrict__ r1, const int* __restrict__ c1, const float* __restrict__ v1,
    const int* __restrict__ r2, const int* __restrict__ c2, const float* __restrict__ v2,
    const int* __restrict__ soff, int2* __restrict__ ebuf, int nnz, int nb) {
  __shared__ int cur[MAXNB];
  for (int b = threadIdx.x; b < nb; b += 1024)
    cur[b] = soff[b * NBLK + blockIdx.x];
  __syncthreads();
  const int tot = 2 * nnz;
  const int chunk = (tot + NBLK - 1) / NBLK;
  const int e0 = blockIdx.x * chunk;
  const int e1 = min(tot, e0 + chunk);
  for (int e = e0 + threadIdx.x; e < e1; e += 1024) {
    int r, c;
    float v;
    if (e < nnz) {
      r = r1[e]; c = c1[e]; v = v1[e];
    } else {
      r = r2[e - nnz]; c = c2[e - nnz]; v = v2[e - nnz];
    }
    const int b = r >> RPB_SH;
    const int slot = atomicAdd(&cur[b], 1);
    ebuf[slot] = make_int2(((r & (RPB - 1)) << 24) | (c << 7), __float_as_int(v));
  }
}

// ---------------------------------------------------------------------------
// Phase D: in-bucket counting sort (one block per bucket). 512 thr, 36 KB LDS.
// Emits row_ptr.
// ---------------------------------------------------------------------------
__global__ __launch_bounds__(512) void sortB_kernel(
    const int* __restrict__ soff, int2* __restrict__ ebuf,
    int* __restrict__ row_ptr, int* __restrict__ bflag,
    int n, int nb, int tot) {
  __shared__ int2 raw[CAP];   // 36 KB
  __shared__ int hist[RPB];
  __shared__ int sc[RPB];
  __shared__ int cur[RPB];
  const int b = blockIdx.x;
  const int beg = soff[b * NBLK];
  const int end = (b + 1 < nb) ? soff[(b + 1) * NBLK] : tot;
  const int cnt = end - beg;

  if (b == nb - 1 && threadIdx.x == 0) row_ptr[n] = tot;

  if (cnt > CAP) {  // degenerate distribution: leave unsorted, flag for gather
    if (threadIdx.x == 0) bflag[b] = 1;
    const int r0 = b * RPB;
    for (int r = threadIdx.x; r < RPB; r += 512) {
      const int gr = r0 + r;
      if (gr < n) row_ptr[gr] = beg;
    }
    return;
  }
  if (threadIdx.x == 0) bflag[b] = 0;
  if (threadIdx.x < RPB) hist[threadIdx.x] = 0;
  __syncthreads();

  for (int i = threadIdx.x; i < cnt; i += 512) {
    const int2 rec = ebuf[beg + i];
    raw[i] = rec;
    atomicAdd(&hist[rec.x >> 24], 1);
  }
  __syncthreads();

  int v = 0;
  if (threadIdx.x < RPB) {
    v = hist[threadIdx.x];
    sc[threadIdx.x] = v;
  }
  __syncthreads();
  for (int off = 1; off < RPB; off <<= 1) {
    int t = 0;
    if (threadIdx.x < RPB && threadIdx.x >= off) t = sc[threadIdx.x - off];
    __syncthreads();
    if (threadIdx.x < RPB) sc[threadIdx.x] += t;
    __syncthreads();
  }
  if (threadIdx.x < RPB) {
    const int ex = sc[threadIdx.x] - v;
    cur[threadIdx.x] = ex;
    const int gr = b * RPB + threadIdx.x;
    if (gr < n) row_ptr[gr] = beg + ex;
  }
  __syncthreads();

  for (int i = threadIdx.x; i < cnt; i += 512) {
    const int2 rec = raw[i];
    const int pos = atomicAdd(&cur[rec.x >> 24], 1);
    ebuf[beg + pos] = rec;
  }
}

// ---------------------------------------------------------------------------
// Phase E: row gather — 8-lane-group dwordx4 scheme. Lane owns 8 channels
// (uint4); the 8 groups process 8 edges per wave-instruction. Per 16 edges:
// 2 record loads + 2 uint4 gathers (vs 8+8 for the dword scheme).
// 3-level shfl_xor butterfly merges groups; fused linear term + sigmoid.
// ---------------------------------------------------------------------------
__global__ __launch_bounds__(256) void gather_kernel(
    const int* __restrict__ row_ptr, const int* __restrict__ soff,
    const int* __restrict__ bflag, const int2* __restrict__ ebuf,
    const char* __restrict__ xwbytes, float4* __restrict__ outf4,
    int n, int nb, int tot) {
  const int lane = threadIdx.x & 63;
  const int g = lane >> 3;        // edge slot 0..7
  const int l8 = lane & 7;        // channel-quad index
  const int l8b = l8 << 4;        // byte offset within row
  const int w = (blockIdx.x * blockDim.x + threadIdx.x) >> 6;
  const int nw = (gridDim.x * blockDim.x) >> 6;

  for (int row = w; row < n; row += nw) {
    // linear term (same addresses for every group -> broadcast loads)
    const float4 lin0 = outf4[(size_t)row * 16 + 2 * l8];
    const float4 lin1 = outf4[(size_t)row * 16 + 2 * l8 + 1];

    float a[8];
#pragma unroll
    for (int k = 0; k < 8; ++k) a[k] = 0.f;

    const int b = row >> RPB_SH;
    if (bflag[b]) {  // degenerate oversized bucket: predicated scan
      const int bb = soff[b * NBLK];
      const int be = (b + 1 < nb) ? soff[(b + 1) * NBLK] : tot;
      const int rl = row & (RPB - 1);
      for (int e = bb; e < be; ++e) {
        const int2 rec = ebuf[e];
        if ((rec.x >> 24) == rl && g == 0) {
          const uint4 u = *(const uint4*)(xwbytes + (rec.x & COLOFF_MASK) + l8b);
          const float v = __int_as_float(rec.y);
          a[0] = fmaf(v, bflo(u.x), a[0]); a[1] = fmaf(v, bfhi(u.x), a[1]);
          a[2] = fmaf(v, bflo(u.y), a[2]); a[3] = fmaf(v, bfhi(u.y), a[3]);
          a[4] = fmaf(v, bflo(u.z), a[4]); a[5] = fmaf(v, bfhi(u.z), a[5]);
          a[6] = fmaf(v, bflo(u.w), a[6]); a[7] = fmaf(v, bfhi(u.w), a[7]);
        }
      }
    } else {
      const int beg = row_ptr[row];
      const int end = row_ptr[row + 1];
      int e = beg;
      for (; e + 16 <= end; e += 16) {
        const int2 rc0 = ebuf[e + g];
        const int2 rc1 = ebuf[e + 8 + g];
        const uint4 u0 = *(const uint4*)(xwbytes + (rc0.x & COLOFF_MASK) + l8b);
        const uint4 u1 = *(const uint4*)(xwbytes + (rc1.x & COLOFF_MASK) + l8b);
        const float v0 = __int_as_float(rc0.y);
        const float v1 = __int_as_float(rc1.y);
        a[0] = fmaf(v0, bflo(u0.x), a[0]); a[1] = fmaf(v0, bfhi(u0.x), a[1]);
        a[2] = fmaf(v0, bflo(u0.y), a[2]); a[3] = fmaf(v0, bfhi(u0.y), a[3]);
        a[4] = fmaf(v0, bflo(u0.z), a[4]); a[5] = fmaf(v0, bfhi(u0.z), a[5]);
        a[6] = fmaf(v0, bflo(u0.w), a[6]); a[7] = fmaf(v0, bfhi(u0.w), a[7]);
        a[0] = fmaf(v1, bflo(u1.x), a[0]); a[1] = fmaf(v1, bfhi(u1.x), a[1]);
        a[2] = fmaf(v1, bflo(u1.y), a[2]); a[3] = fmaf(v1, bfhi(u1.y), a[3]);
        a[4] = fmaf(v1, bflo(u1.z), a[4]); a[5] = fmaf(v1, bfhi(u1.z), a[5]);
        a[6] = fmaf(v1, bflo(u1.w), a[6]); a[7] = fmaf(v1, bfhi(u1.w), a[7]);
      }
      for (; e < end; e += 8) {
        const int idx = e + g;
        const bool ok = idx < end;
        const int2 rc = ebuf[ok ? idx : (end - 1)];
        const uint4 u = *(const uint4*)(xwbytes + (rc.x & COLOFF_MASK) + l8b);
        const float v = ok ? __int_as_float(rc.y) : 0.f;
        a[0] = fmaf(v, bflo(u.x), a[0]); a[1] = fmaf(v, bfhi(u.x), a[1]);
        a[2] = fmaf(v, bflo(u.y), a[2]); a[3] = fmaf(v, bfhi(u.y), a[3]);
        a[4] = fmaf(v, bflo(u.z), a[4]); a[5] = fmaf(v, bfhi(u.z), a[5]);
        a[6] = fmaf(v, bflo(u.w), a[6]); a[7] = fmaf(v, bfhi(u.w), a[7]);
      }
    }

    // butterfly merge across the 8 groups
#pragma unroll
    for (int k = 0; k < 8; ++k) {
      a[k] += __shfl_xor(a[k], 8, 64);
      a[k] += __shfl_xor(a[k], 16, 64);
      a[k] += __shfl_xor(a[k], 32, 64);
    }

    if (lane < 8) {  // g == 0: l8 = lane
      float4 o0, o1;
      o0.x = 1.f / (1.f + __expf(-(lin0.x + a[0])));
      o0.y = 1.f / (1.f + __expf(-(lin0.y + a[1])));
      o0.z = 1.f / (1.f + __expf(-(lin0.z + a[2])));
      o0.w = 1.f / (1.f + __expf(-(lin0.w + a[3])));
      o1.x = 1.f / (1.f + __expf(-(lin1.x + a[4])));
      o1.y = 1.f / (1.f + __expf(-(lin1.y + a[5])));
      o1.z = 1.f / (1.f + __expf(-(lin1.z + a[6])));
      o1.w = 1.f / (1.f + __expf(-(lin1.w + a[7])));
      outf4[(size_t)row * 16 + 2 * l8] = o0;
      outf4[(size_t)row * 16 + 2 * l8 + 1] = o1;
    }
  }
}

// ---------------------------------------------------------------------------
// Fallback path (ws too small): atomic scatter + sigmoid.
// ---------------------------------------------------------------------------
__global__ __launch_bounds__(256) void scatter_kernel(
    const int* __restrict__ rows, const int* __restrict__ cols,
    const float* __restrict__ vals, const unsigned short* __restrict__ xwb,
    float* __restrict__ out, int nnz) {
  const int lane = threadIdx.x & 63;
  const int wid = (blockIdx.x * blockDim.x + threadIdx.x) >> 6;
  const int nwaves = (gridDim.x * blockDim.x) >> 6;
  for (int k = wid; k < nnz; k += nwaves) {
    const float xv = bf2f(xwb[(size_t)cols[k] * CH + lane]);
    atomicAdd(&out[(size_t)rows[k] * CH + lane], vals[k] * xv);
  }
}

__global__ __launch_bounds__(256) void sigmoid_kernel(float* __restrict__ out, int n4) {
  const int i = blockIdx.x * blockDim.x + threadIdx.x;
  if (i < n4) {
    float4 v = reinterpret_cast<float4*>(out)[i];
    v.x = 1.f / (1.f + __expf(-v.x));
    v.y = 1.f / (1.f + __expf(-v.y));
    v.z = 1.f / (1.f + __expf(-v.z));
    v.w = 1.f / (1.f + __expf(-v.w));
    reinterpret_cast<float4*>(out)[i] = v;
  }
}

extern "C" void kernel_launch(void* const* d_in, const int* in_sizes, int n_in,
                              void* d_out, int out_size, void* d_ws, size_t ws_size,
                              hipStream_t stream) {
  const float* x         = (const float*)d_in[0];
  const int*   down_rows = (const int*)d_in[1];
  const int*   down_cols = (const int*)d_in[2];
  const float* down_vals = (const float*)d_in[3];
  const int*   up_rows   = (const int*)d_in[4];
  const int*   up_cols   = (const int*)d_in[5];
  const float* up_vals   = (const float*)d_in[6];
  const float* w_conv    = (const float*)d_in[7];
  const float* w_lin     = (const float*)d_in[8];

  const int n   = in_sizes[0] / CH;  // 100000
  const int nnz = in_sizes[1];       // 1600000
  const int tot = 2 * nnz;
  const int nb  = (n + RPB - 1) / RPB;  // 782

  float* out = (float*)d_out;

  // ws layout (xw stored as bf16)
  char* p = (char*)d_ws;
  unsigned short* xwb = (unsigned short*)p;  p += (size_t)n * CH * 2;
  int* soff    = (int*)p;  p += (size_t)nb * NBLK * 4;
  int* partial = (int*)p;  p += 1024 * 4;
  int* row_ptr = (int*)p;  p += ((size_t)n + 2) * 4;
  int* bflag   = (int*)p;  p += (size_t)nb * 4;
  p = (char*)(((uintptr_t)p + 15) & ~(uintptr_t)15);
  int2* ebuf   = (int2*)p; p += (size_t)tot * 8;
  const size_t need = (size_t)(p - (char*)d_ws);

  if (ws_size >= need && nb <= MAXNB && n < (1 << 17)) {
    // GEMM (blocks 0..1023) + countT (blocks 1024..1279) in one launch
    gemm_count_kernel<<<GEMM_BLOCKS + NBLK, 256, 0, stream>>>(
        x, w_conv, w_lin, xwb, out, n, down_rows, up_rows, soff, nnz, nb);
    const int ntot = nb * NBLK;
    const int nsb = (ntot + SCAN_B - 1) / SCAN_B;  // 391 <= 1024
    scan_partial<<<nsb, SCAN_B, 0, stream>>>(soff, partial, ntot);
    scan_partials_scan<<<1, 1024, 0, stream>>>(partial, nsb);
    scan_final<<<nsb, SCAN_B, 0, stream>>>(soff, partial, ntot);
    fillB_kernel<<<NBLK, 1024, 0, stream>>>(down_rows, down_cols, down_vals,
                                            up_rows, up_cols, up_vals,
                                            soff, ebuf, nnz, nb);
    sortB_kernel<<<nb, 512, 0, stream>>>(soff, ebuf, row_ptr, bflag, n, nb, tot);
    const int nblk = (n + 3) / 4;
    gather_kernel<<<nblk, 256, 0, stream>>>(row_ptr, soff, bflag, ebuf,
                                            (const char*)xwb,
                                            (float4*)out, n, nb, tot);
  } else {
    // fallback: gemm only (nb=0 disables count work; countsT ptr unused)
    gemm_count_kernel<<<GEMM_BLOCKS, 256, 0, stream>>>(
        x, w_conv, w_lin, xwb, out, n, down_rows, up_rows, (int*)d_ws, nnz, 0);
    scatter_kernel<<<4096, 256, 0, stream>>>(down_rows, down_cols, down_vals, xwb, out, nnz);
    scatter_kernel<<<4096, 256, 0, stream>>>(up_rows, up_cols, up_vals, xwb, out, nnz);
    const int n4 = (n * CH) / 4;
    sigmoid_kernel<<<(n4 + 255) / 256, 256, 0, stream>>>(out, n4);
  }
}

// Round 10
// 150.716 us; speedup vs baseline: 1.2527x; 1.0463x over previous
//
#include <hip/hip_runtime.h>
#include <hip/hip_bf16.h>

#define CH 64
#define RPB 128       // rows per bucket
#define RPB_SH 7
#define MAXNB 800     // max buckets supported by LDS arrays
#define CAPG 4352     // per-bucket region capacity (mean 4096 + 4 sigma)
#define BATCH 4096    // fill staging batch (LDS)
#define SPILLMAX 16384
#define GEMM_BLOCKS 1024
#define FILL_BLOCKS 256

typedef __attribute__((ext_vector_type(8))) short short8;
typedef __attribute__((ext_vector_type(4))) float f32x4;

__device__ __forceinline__ unsigned short f2bf(float f) {
  unsigned int u = __float_as_uint(f);
  u = u + 0x7FFFu + ((u >> 16) & 1u);  // RNE
  return (unsigned short)(u >> 16);
}
__device__ __forceinline__ float bf2f(unsigned short s) {
  return __uint_as_float(((unsigned int)s) << 16);
}
__device__ __forceinline__ float bflo(unsigned int u) {
  return __uint_as_float(u << 16);
}
__device__ __forceinline__ float bfhi(unsigned int u) {
  return __uint_as_float(u & 0xFFFF0000u);
}

// record: rec.x = (local_row << 24) | (col << 7)  [col*128 = xw row byte offset]
//         rec.y = fp32 val bits
#define COLOFF_MASK 0x00FFFF80

// ---------------------------------------------------------------------------
// Kernel 1: fused dual GEMM via MFMA, split-bf16 for fp32-grade accuracy.
// Waves 0-1: xw = x@w_conv -> bf16 ws.  Waves 2-3: out = x@w_lin -> fp32.
// ---------------------------------------------------------------------------
__global__ __launch_bounds__(256) void gemm_kernel(
    const float* __restrict__ x, const float* __restrict__ wc,
    const float* __restrict__ wl, unsigned short* __restrict__ xwb,
    float* __restrict__ out, int n) {
  const int lane = threadIdx.x & 63;
  const int wv = threadIdx.x >> 6;
  const int mat = wv >> 1;   // 0: conv, 1: lin
  const int tile = wv & 1;   // row-tile within 32-row group
  const float* __restrict__ W = mat ? wl : wc;

  const int i16 = lane & 15;
  const int kseg = lane >> 4;

  short8 bhi[4][2], blo[4][2];
#pragma unroll
  for (int nt = 0; nt < 4; ++nt)
#pragma unroll
    for (int kk = 0; kk < 2; ++kk)
#pragma unroll
      for (int j = 0; j < 8; ++j) {
        const float w = W[(kk * 32 + kseg * 8 + j) * CH + nt * 16 + i16];
        const unsigned short hh = f2bf(w);
        bhi[nt][kk][j] = (short)hh;
        blo[nt][kk][j] = (short)f2bf(w - bf2f(hh));
      }

  const int ngroups = (n + 31) >> 5;
  for (int g = blockIdx.x; g < ngroups; g += GEMM_BLOCKS) {
    const int base = g * 32 + tile * 16;
    const int row = base + i16;
    const int rowc = (row < n) ? row : (n - 1);
    const float* xp = x + (size_t)rowc * CH + kseg * 8;

    float af[16];
    {
      const float4 p0 = *(const float4*)(xp);
      const float4 p1 = *(const float4*)(xp + 4);
      const float4 q0 = *(const float4*)(xp + 32);
      const float4 q1 = *(const float4*)(xp + 36);
      af[0] = p0.x; af[1] = p0.y; af[2] = p0.z; af[3] = p0.w;
      af[4] = p1.x; af[5] = p1.y; af[6] = p1.z; af[7] = p1.w;
      af[8] = q0.x; af[9] = q0.y; af[10] = q0.z; af[11] = q0.w;
      af[12] = q1.x; af[13] = q1.y; af[14] = q1.z; af[15] = q1.w;
    }
    short8 ahi[2], alo[2];
#pragma unroll
    for (int kk = 0; kk < 2; ++kk)
#pragma unroll
      for (int j = 0; j < 8; ++j) {
        const float f = af[kk * 8 + j];
        const unsigned short hh = f2bf(f);
        ahi[kk][j] = (short)hh;
        alo[kk][j] = (short)f2bf(f - bf2f(hh));
      }

    f32x4 acc[4];
#pragma unroll
    for (int nt = 0; nt < 4; ++nt) {
      f32x4 a = {0.f, 0.f, 0.f, 0.f};
#pragma unroll
      for (int kk = 0; kk < 2; ++kk) {
        a = __builtin_amdgcn_mfma_f32_16x16x32_bf16(ahi[kk], bhi[nt][kk], a, 0, 0, 0);
        a = __builtin_amdgcn_mfma_f32_16x16x32_bf16(alo[kk], bhi[nt][kk], a, 0, 0, 0);
        a = __builtin_amdgcn_mfma_f32_16x16x32_bf16(ahi[kk], blo[nt][kk], a, 0, 0, 0);
      }
      acc[nt] = a;
    }

    if (mat == 0) {
#pragma unroll
      for (int nt = 0; nt < 4; ++nt)
#pragma unroll
        for (int r = 0; r < 4; ++r) {
          const int orow = base + kseg * 4 + r;
          if (orow < n)
            xwb[(size_t)orow * CH + nt * 16 + i16] = f2bf(acc[nt][r]);
        }
    } else {
#pragma unroll
      for (int nt = 0; nt < 4; ++nt)
#pragma unroll
        for (int r = 0; r < 4; ++r) {
          const int orow = base + kseg * 4 + r;
          if (orow < n)
            out[(size_t)orow * CH + nt * 16 + i16] = acc[nt][r];
        }
    }
  }
}

// ---------------------------------------------------------------------------
// Fill with runtime reservation: batches of 4096 edges staged in LDS,
// per-bucket LDS histogram, ONE global atomicAdd per (bucket,batch) reserves
// a contiguous run in the bucket's fixed region; scatter from LDS.
// Replaces countT + 3 scan launches. Overflow -> spill list (empty in practice).
// ---------------------------------------------------------------------------
__global__ __launch_bounds__(1024) void fillR_kernel(
    const int* __restrict__ r1, const int* __restrict__ c1, const float* __restrict__ v1,
    const int* __restrict__ r2, const int* __restrict__ c2, const float* __restrict__ v2,
    int* __restrict__ gcur, int* __restrict__ spillcnt, int4* __restrict__ spill,
    int2* __restrict__ ebuf, int nnz, int nb) {
  __shared__ int2 stash[BATCH];          // 32 KB
  __shared__ unsigned short sbuck[BATCH];// 8 KB
  __shared__ int hist[MAXNB];            // 3.2 KB
  __shared__ int rbase[MAXNB];           // 3.2 KB
  const int tid = threadIdx.x;
  const int tot = 2 * nnz;
  const int nbatches = (tot + BATCH - 1) / BATCH;

  for (int bt = blockIdx.x; bt < nbatches; bt += gridDim.x) {
    for (int i = tid; i < nb; i += 1024) hist[i] = 0;
    __syncthreads();

    const int e0 = bt * BATCH;
    const int m = min(BATCH, tot - e0);
    for (int i = tid; i < m; i += 1024) {
      const int e = e0 + i;
      int r, c;
      float v;
      if (e < nnz) {
        r = r1[e]; c = c1[e]; v = v1[e];
      } else {
        r = r2[e - nnz]; c = c2[e - nnz]; v = v2[e - nnz];
      }
      const int b = r >> RPB_SH;
      stash[i] = make_int2(((r & (RPB - 1)) << 24) | (c << 7), __float_as_int(v));
      sbuck[i] = (unsigned short)b;
      atomicAdd(&hist[b], 1);
    }
    __syncthreads();

    for (int b = tid; b < nb; b += 1024) {
      const int c = hist[b];
      rbase[b] = c ? atomicAdd(&gcur[b], c) : 0;
      hist[b] = 0;  // reuse as local placement cursor
    }
    __syncthreads();

    for (int i = tid; i < m; i += 1024) {
      const int b = sbuck[i];
      const int2 rec = stash[i];
      const int p = rbase[b] + atomicAdd(&hist[b], 1);
      if (p < CAPG) {
        ebuf[(size_t)b * CAPG + p] = rec;
      } else {
        const int sp = atomicAdd(spillcnt, 1);
        if (sp < SPILLMAX)
          spill[sp] = make_int4(b * RPB + (rec.x >> 24), rec.x & COLOFF_MASK,
                                rec.y, 0);
      }
    }
    __syncthreads();
  }
}

// ---------------------------------------------------------------------------
// In-bucket counting sort (one block per bucket). 512 thr, ~36 KB LDS.
// Emits packed rowinfo[gr] = (row_start_offset << 16) | row_count.
// ---------------------------------------------------------------------------
__global__ __launch_bounds__(512) void sortB_kernel(
    const int* __restrict__ gcur, int2* __restrict__ ebuf,
    unsigned int* __restrict__ rowinfo, int n, int nb) {
  __shared__ int2 raw[CAPG];  // 34.8 KB
  __shared__ int hist[RPB];
  __shared__ int sc[RPB];
  __shared__ int cur[RPB];
  const int b = blockIdx.x;
  const int beg = b * CAPG;
  const int cnt = min(gcur[b], CAPG);

  if (threadIdx.x < RPB) hist[threadIdx.x] = 0;
  __syncthreads();

  for (int i = threadIdx.x; i < cnt; i += 512) {
    const int2 rec = ebuf[beg + i];
    raw[i] = rec;
    atomicAdd(&hist[rec.x >> 24], 1);
  }
  __syncthreads();

  int v = 0;
  if (threadIdx.x < RPB) {
    v = hist[threadIdx.x];
    sc[threadIdx.x] = v;
  }
  __syncthreads();
  for (int off = 1; off < RPB; off <<= 1) {
    int t = 0;
    if (threadIdx.x < RPB && threadIdx.x >= off) t = sc[threadIdx.x - off];
    __syncthreads();
    if (threadIdx.x < RPB) sc[threadIdx.x] += t;
    __syncthreads();
  }
  if (threadIdx.x < RPB) {
    const int ex = sc[threadIdx.x] - v;  // exclusive start
    cur[threadIdx.x] = ex;
    const int gr = b * RPB + threadIdx.x;
    if (gr < n) rowinfo[gr] = ((unsigned int)ex << 16) | (unsigned int)v;
  }
  __syncthreads();

  for (int i = threadIdx.x; i < cnt; i += 512) {
    const int2 rec = raw[i];
    const int pos = atomicAdd(&cur[rec.x >> 24], 1);
    ebuf[beg + pos] = rec;
  }
}

// ---------------------------------------------------------------------------
// Row gather — 8-lane-group dwordx4 scheme (R9 winner) + spill pass.
// ---------------------------------------------------------------------------
__global__ __launch_bounds__(256) void gather_kernel(
    const unsigned int* __restrict__ rowinfo, const int2* __restrict__ ebuf,
    const char* __restrict__ xwbytes, float4* __restrict__ outf4,
    const int* __restrict__ spillcnt, const int4* __restrict__ spill,
    int n) {
  const int lane = threadIdx.x & 63;
  const int g = lane >> 3;        // edge slot 0..7
  const int l8 = lane & 7;        // channel-quad index
  const int l8b = l8 << 4;        // byte offset within row
  const int w = (blockIdx.x * blockDim.x + threadIdx.x) >> 6;
  const int nw = (gridDim.x * blockDim.x) >> 6;
  const int sc = min(*spillcnt, SPILLMAX);

  for (int row = w; row < n; row += nw) {
    const float4 lin0 = outf4[(size_t)row * 16 + 2 * l8];
    const float4 lin1 = outf4[(size_t)row * 16 + 2 * l8 + 1];

    float a[8];
#pragma unroll
    for (int k = 0; k < 8; ++k) a[k] = 0.f;

    const unsigned int info = rowinfo[row];
    const int beg = (row >> RPB_SH) * CAPG + (int)(info >> 16);
    const int end = beg + (int)(info & 0xFFFFu);

    int e = beg;
    for (; e + 16 <= end; e += 16) {
      const int2 rc0 = ebuf[e + g];
      const int2 rc1 = ebuf[e + 8 + g];
      const uint4 u0 = *(const uint4*)(xwbytes + (rc0.x & COLOFF_MASK) + l8b);
      const uint4 u1 = *(const uint4*)(xwbytes + (rc1.x & COLOFF_MASK) + l8b);
      const float v0 = __int_as_float(rc0.y);
      const float v1 = __int_as_float(rc1.y);
      a[0] = fmaf(v0, bflo(u0.x), a[0]); a[1] = fmaf(v0, bfhi(u0.x), a[1]);
      a[2] = fmaf(v0, bflo(u0.y), a[2]); a[3] = fmaf(v0, bfhi(u0.y), a[3]);
      a[4] = fmaf(v0, bflo(u0.z), a[4]); a[5] = fmaf(v0, bfhi(u0.z), a[5]);
      a[6] = fmaf(v0, bflo(u0.w), a[6]); a[7] = fmaf(v0, bfhi(u0.w), a[7]);
      a[0] = fmaf(v1, bflo(u1.x), a[0]); a[1] = fmaf(v1, bfhi(u1.x), a[1]);
      a[2] = fmaf(v1, bflo(u1.y), a[2]); a[3] = fmaf(v1, bfhi(u1.y), a[3]);
      a[4] = fmaf(v1, bflo(u1.z), a[4]); a[5] = fmaf(v1, bfhi(u1.z), a[5]);
      a[6] = fmaf(v1, bflo(u1.w), a[6]); a[7] = fmaf(v1, bfhi(u1.w), a[7]);
    }
    for (; e < end; e += 8) {
      const int idx = e + g;
      const bool ok = idx < end;
      const int2 rc = ebuf[ok ? idx : (end - 1)];
      const uint4 u = *(const uint4*)(xwbytes + (rc.x & COLOFF_MASK) + l8b);
      const float v = ok ? __int_as_float(rc.y) : 0.f;
      a[0] = fmaf(v, bflo(u.x), a[0]); a[1] = fmaf(v, bfhi(u.x), a[1]);
      a[2] = fmaf(v, bflo(u.y), a[2]); a[3] = fmaf(v, bfhi(u.y), a[3]);
      a[4] = fmaf(v, bflo(u.z), a[4]); a[5] = fmaf(v, bfhi(u.z), a[5]);
      a[6] = fmaf(v, bflo(u.w), a[6]); a[7] = fmaf(v, bfhi(u.w), a[7]);
    }

    if (sc > 0) {  // spill pass (empty in practice; uniform branch)
      for (int s = 0; s < sc; ++s) {
        const int4 r = spill[s];
        if (r.x == row && g == 0) {
          const uint4 u = *(const uint4*)(xwbytes + r.y + l8b);
          const float v = __int_as_float(r.z);
          a[0] = fmaf(v, bflo(u.x), a[0]); a[1] = fmaf(v, bfhi(u.x), a[1]);
          a[2] = fmaf(v, bflo(u.y), a[2]); a[3] = fmaf(v, bfhi(u.y), a[3]);
          a[4] = fmaf(v, bflo(u.z), a[4]); a[5] = fmaf(v, bfhi(u.z), a[5]);
          a[6] = fmaf(v, bflo(u.w), a[6]); a[7] = fmaf(v, bfhi(u.w), a[7]);
        }
      }
    }

    // butterfly merge across the 8 groups
#pragma unroll
    for (int k = 0; k < 8; ++k) {
      a[k] += __shfl_xor(a[k], 8, 64);
      a[k] += __shfl_xor(a[k], 16, 64);
      a[k] += __shfl_xor(a[k], 32, 64);
    }

    if (lane < 8) {  // g == 0: l8 = lane
      float4 o0, o1;
      o0.x = 1.f / (1.f + __expf(-(lin0.x + a[0])));
      o0.y = 1.f / (1.f + __expf(-(lin0.y + a[1])));
      o0.z = 1.f / (1.f + __expf(-(lin0.z + a[2])));
      o0.w = 1.f / (1.f + __expf(-(lin0.w + a[3])));
      o1.x = 1.f / (1.f + __expf(-(lin1.x + a[4])));
      o1.y = 1.f / (1.f + __expf(-(lin1.y + a[5])));
      o1.z = 1.f / (1.f + __expf(-(lin1.z + a[6])));
      o1.w = 1.f / (1.f + __expf(-(lin1.w + a[7])));
      outf4[(size_t)row * 16 + 2 * l8] = o0;
      outf4[(size_t)row * 16 + 2 * l8 + 1] = o1;
    }
  }
}

// ---------------------------------------------------------------------------
// Fallback path (ws too small): atomic scatter + sigmoid.
// ---------------------------------------------------------------------------
__global__ __launch_bounds__(256) void scatter_kernel(
    const int* __restrict__ rows, const int* __restrict__ cols,
    const float* __restrict__ vals, const unsigned short* __restrict__ xwb,
    float* __restrict__ out, int nnz) {
  const int lane = threadIdx.x & 63;
  const int wid = (blockIdx.x * blockDim.x + threadIdx.x) >> 6;
  const int nwaves = (gridDim.x * blockDim.x) >> 6;
  for (int k = wid; k < nnz; k += nwaves) {
    const float xv = bf2f(xwb[(size_t)cols[k] * CH + lane]);
    atomicAdd(&out[(size_t)rows[k] * CH + lane], vals[k] * xv);
  }
}

__global__ __launch_bounds__(256) void sigmoid_kernel(float* __restrict__ out, int n4) {
  const int i = blockIdx.x * blockDim.x + threadIdx.x;
  if (i < n4) {
    float4 v = reinterpret_cast<float4*>(out)[i];
    v.x = 1.f / (1.f + __expf(-v.x));
    v.y = 1.f / (1.f + __expf(-v.y));
    v.z = 1.f / (1.f + __expf(-v.z));
    v.w = 1.f / (1.f + __expf(-v.w));
    reinterpret_cast<float4*>(out)[i] = v;
  }
}

extern "C" void kernel_launch(void* const* d_in, const int* in_sizes, int n_in,
                              void* d_out, int out_size, void* d_ws, size_t ws_size,
                              hipStream_t stream) {
  const float* x         = (const float*)d_in[0];
  const int*   down_rows = (const int*)d_in[1];
  const int*   down_cols = (const int*)d_in[2];
  const float* down_vals = (const float*)d_in[3];
  const int*   up_rows   = (const int*)d_in[4];
  const int*   up_cols   = (const int*)d_in[5];
  const float* up_vals   = (const float*)d_in[6];
  const float* w_conv    = (const float*)d_in[7];
  const float* w_lin     = (const float*)d_in[8];

  const int n   = in_sizes[0] / CH;  // 100000
  const int nnz = in_sizes[1];       // 1600000
  const int nb  = (n + RPB - 1) / RPB;  // 782

  float* out = (float*)d_out;

  // ws layout
  char* p = (char*)d_ws;
  unsigned short* xwb = (unsigned short*)p;  p += (size_t)n * CH * 2;
  int* gcur    = (int*)p;  p += (size_t)nb * 4;
  int* spillc  = (int*)p;  p += 16;           // spill counter (+pad)
  unsigned int* rowinfo = (unsigned int*)p;  p += ((size_t)n + 2) * 4;
  p = (char*)(((uintptr_t)p + 15) & ~(uintptr_t)15);
  int4* spill  = (int4*)p; p += (size_t)SPILLMAX * 16;
  int2* ebuf   = (int2*)p; p += (size_t)nb * CAPG * 8;
  const size_t need = (size_t)(p - (char*)d_ws);

  if (ws_size >= need && nb <= MAXNB && n < (1 << 17)) {
    hipMemsetAsync(gcur, 0, (size_t)nb * 4 + 16, stream);  // gcur + spillc
    gemm_kernel<<<GEMM_BLOCKS, 256, 0, stream>>>(x, w_conv, w_lin, xwb, out, n);
    fillR_kernel<<<FILL_BLOCKS, 1024, 0, stream>>>(
        down_rows, down_cols, down_vals, up_rows, up_cols, up_vals,
        gcur, spillc, spill, ebuf, nnz, nb);
    sortB_kernel<<<nb, 512, 0, stream>>>(gcur, ebuf, rowinfo, n, nb);
    const int nblk = (n + 3) / 4;
    gather_kernel<<<nblk, 256, 0, stream>>>(rowinfo, ebuf, (const char*)xwb,
                                            (float4*)out, spillc, spill, n);
  } else {
    gemm_kernel<<<GEMM_BLOCKS, 256, 0, stream>>>(x, w_conv, w_lin, xwb, out, n);
    scatter_kernel<<<4096, 256, 0, stream>>>(down_rows, down_cols, down_vals, xwb, out, nnz);
    scatter_kernel<<<4096, 256, 0, stream>>>(up_rows, up_cols, up_vals, xwb, out, nnz);
    const int n4 = (n * CH) / 4;
    sigmoid_kernel<<<(n4 + 255) / 256, 256, 0, stream>>>(out, n4);
  }
}

// Round 11
// 147.623 us; speedup vs baseline: 1.2790x; 1.0209x over previous
//
#include <hip/hip_runtime.h>
#include <hip/hip_bf16.h>
#include <hip/hip_fp16.h>

#define CH 64
#define RPB 128       // rows per bucket
#define RPB_SH 7
#define MAXNB 800     // max buckets supported by LDS arrays
#define CAPG 4352     // per-bucket region capacity (mean 4096 + 4 sigma)
#define BATCH 4096    // fill staging batch (LDS)
#define SPILLMAX 16384
#define GEMM_BLOCKS 1024
#define FILL_BLOCKS 256

typedef __attribute__((ext_vector_type(8))) _Float16 half8;
typedef __attribute__((ext_vector_type(4))) float f32x4;

// record: rec.x = (local_row << 24) | (col << 7)  [col*128 = xw row byte offset]
//         rec.y = fp32 val bits
#define COLOFF_MASK 0x00FFFF80

// ---------------------------------------------------------------------------
// Kernel 1: fused dual GEMM via MFMA, split-fp16 (x=hi+lo, W=whi+wlo) for
// fp32-grade accuracy.  Waves 0-1: xw = x@w_conv -> fp16 ws.
//                       Waves 2-3: out = x@w_lin -> fp32 d_out.
// ---------------------------------------------------------------------------
__global__ __launch_bounds__(256) void gemm_kernel(
    const float* __restrict__ x, const float* __restrict__ wc,
    const float* __restrict__ wl, __half* __restrict__ xwh,
    float* __restrict__ out, int n) {
  const int lane = threadIdx.x & 63;
  const int wv = threadIdx.x >> 6;
  const int mat = wv >> 1;   // 0: conv, 1: lin
  const int tile = wv & 1;   // row-tile within 32-row group
  const float* __restrict__ W = mat ? wl : wc;

  const int i16 = lane & 15;
  const int kseg = lane >> 4;

  half8 bhi[4][2], blo[4][2];
#pragma unroll
  for (int nt = 0; nt < 4; ++nt)
#pragma unroll
    for (int kk = 0; kk < 2; ++kk)
#pragma unroll
      for (int j = 0; j < 8; ++j) {
        const float w = W[(kk * 32 + kseg * 8 + j) * CH + nt * 16 + i16];
        const _Float16 hh = (_Float16)w;
        bhi[nt][kk][j] = hh;
        blo[nt][kk][j] = (_Float16)(w - (float)hh);
      }

  const int ngroups = (n + 31) >> 5;
  for (int g = blockIdx.x; g < ngroups; g += GEMM_BLOCKS) {
    const int base = g * 32 + tile * 16;
    const int row = base + i16;
    const int rowc = (row < n) ? row : (n - 1);
    const float* xp = x + (size_t)rowc * CH + kseg * 8;

    float af[16];
    {
      const float4 p0 = *(const float4*)(xp);
      const float4 p1 = *(const float4*)(xp + 4);
      const float4 q0 = *(const float4*)(xp + 32);
      const float4 q1 = *(const float4*)(xp + 36);
      af[0] = p0.x; af[1] = p0.y; af[2] = p0.z; af[3] = p0.w;
      af[4] = p1.x; af[5] = p1.y; af[6] = p1.z; af[7] = p1.w;
      af[8] = q0.x; af[9] = q0.y; af[10] = q0.z; af[11] = q0.w;
      af[12] = q1.x; af[13] = q1.y; af[14] = q1.z; af[15] = q1.w;
    }
    half8 ahi[2], alo[2];
#pragma unroll
    for (int kk = 0; kk < 2; ++kk)
#pragma unroll
      for (int j = 0; j < 8; ++j) {
        const float f = af[kk * 8 + j];
        const _Float16 hh = (_Float16)f;
        ahi[kk][j] = hh;
        alo[kk][j] = (_Float16)(f - (float)hh);
      }

    f32x4 acc[4];
#pragma unroll
    for (int nt = 0; nt < 4; ++nt) {
      f32x4 a = {0.f, 0.f, 0.f, 0.f};
#pragma unroll
      for (int kk = 0; kk < 2; ++kk) {
        a = __builtin_amdgcn_mfma_f32_16x16x32_f16(ahi[kk], bhi[nt][kk], a, 0, 0, 0);
        a = __builtin_amdgcn_mfma_f32_16x16x32_f16(alo[kk], bhi[nt][kk], a, 0, 0, 0);
        a = __builtin_amdgcn_mfma_f32_16x16x32_f16(ahi[kk], blo[nt][kk], a, 0, 0, 0);
      }
      acc[nt] = a;
    }

    if (mat == 0) {
#pragma unroll
      for (int nt = 0; nt < 4; ++nt)
#pragma unroll
        for (int r = 0; r < 4; ++r) {
          const int orow = base + kseg * 4 + r;
          if (orow < n)
            xwh[(size_t)orow * CH + nt * 16 + i16] = __float2half(acc[nt][r]);
        }
    } else {
#pragma unroll
      for (int nt = 0; nt < 4; ++nt)
#pragma unroll
        for (int r = 0; r < 4; ++r) {
          const int orow = base + kseg * 4 + r;
          if (orow < n)
            out[(size_t)orow * CH + nt * 16 + i16] = acc[nt][r];
        }
    }
  }
}

// ---------------------------------------------------------------------------
// Fill with runtime reservation (R10 winner): batches of 4096 edges staged in
// LDS, per-bucket LDS histogram, ONE global atomicAdd per (bucket,batch)
// reserves a contiguous run in the bucket's region; scatter from LDS.
// ---------------------------------------------------------------------------
__global__ __launch_bounds__(1024) void fillR_kernel(
    const int* __restrict__ r1, const int* __restrict__ c1, const float* __restrict__ v1,
    const int* __restrict__ r2, const int* __restrict__ c2, const float* __restrict__ v2,
    int* __restrict__ gcur, int* __restrict__ spillcnt, int4* __restrict__ spill,
    int2* __restrict__ ebuf, int nnz, int nb) {
  __shared__ int2 stash[BATCH];          // 32 KB
  __shared__ unsigned short sbuck[BATCH];// 8 KB
  __shared__ int hist[MAXNB];            // 3.2 KB
  __shared__ int rbase[MAXNB];           // 3.2 KB
  const int tid = threadIdx.x;
  const int tot = 2 * nnz;
  const int nbatches = (tot + BATCH - 1) / BATCH;

  for (int bt = blockIdx.x; bt < nbatches; bt += gridDim.x) {
    for (int i = tid; i < nb; i += 1024) hist[i] = 0;
    __syncthreads();

    const int e0 = bt * BATCH;
    const int m = min(BATCH, tot - e0);
    for (int i = tid; i < m; i += 1024) {
      const int e = e0 + i;
      int r, c;
      float v;
      if (e < nnz) {
        r = r1[e]; c = c1[e]; v = v1[e];
      } else {
        r = r2[e - nnz]; c = c2[e - nnz]; v = v2[e - nnz];
      }
      const int b = r >> RPB_SH;
      stash[i] = make_int2(((r & (RPB - 1)) << 24) | (c << 7), __float_as_int(v));
      sbuck[i] = (unsigned short)b;
      atomicAdd(&hist[b], 1);
    }
    __syncthreads();

    for (int b = tid; b < nb; b += 1024) {
      const int c = hist[b];
      rbase[b] = c ? atomicAdd(&gcur[b], c) : 0;
      hist[b] = 0;  // reuse as local placement cursor
    }
    __syncthreads();

    for (int i = tid; i < m; i += 1024) {
      const int b = sbuck[i];
      const int2 rec = stash[i];
      const int p = rbase[b] + atomicAdd(&hist[b], 1);
      if (p < CAPG) {
        ebuf[(size_t)b * CAPG + p] = rec;
      } else {
        const int sp = atomicAdd(spillcnt, 1);
        if (sp < SPILLMAX)
          spill[sp] = make_int4(b * RPB + (rec.x >> 24), rec.x & COLOFF_MASK,
                                rec.y, 0);
      }
    }
    __syncthreads();
  }
}

// ---------------------------------------------------------------------------
// In-bucket counting sort (one block per bucket). 512 thr, ~36 KB LDS.
// Emits packed rowinfo[gr] = (row_start_offset << 16) | row_count.
// ---------------------------------------------------------------------------
__global__ __launch_bounds__(512) void sortB_kernel(
    const int* __restrict__ gcur, int2* __restrict__ ebuf,
    unsigned int* __restrict__ rowinfo, int n, int nb) {
  __shared__ int2 raw[CAPG];  // 34.8 KB
  __shared__ int hist[RPB];
  __shared__ int sc[RPB];
  __shared__ int cur[RPB];
  const int b = blockIdx.x;
  const int beg = b * CAPG;
  const int cnt = min(gcur[b], CAPG);

  if (threadIdx.x < RPB) hist[threadIdx.x] = 0;
  __syncthreads();

  for (int i = threadIdx.x; i < cnt; i += 512) {
    const int2 rec = ebuf[beg + i];
    raw[i] = rec;
    atomicAdd(&hist[rec.x >> 24], 1);
  }
  __syncthreads();

  int v = 0;
  if (threadIdx.x < RPB) {
    v = hist[threadIdx.x];
    sc[threadIdx.x] = v;
  }
  __syncthreads();
  for (int off = 1; off < RPB; off <<= 1) {
    int t = 0;
    if (threadIdx.x < RPB && threadIdx.x >= off) t = sc[threadIdx.x - off];
    __syncthreads();
    if (threadIdx.x < RPB) sc[threadIdx.x] += t;
    __syncthreads();
  }
  if (threadIdx.x < RPB) {
    const int ex = sc[threadIdx.x] - v;  // exclusive start
    cur[threadIdx.x] = ex;
    const int gr = b * RPB + threadIdx.x;
    if (gr < n) rowinfo[gr] = ((unsigned int)ex << 16) | (unsigned int)v;
  }
  __syncthreads();

  for (int i = threadIdx.x; i < cnt; i += 512) {
    const int2 rec = raw[i];
    const int pos = atomicAdd(&cur[rec.x >> 24], 1);
    ebuf[beg + pos] = rec;
  }
}

// ---------------------------------------------------------------------------
// Row gather — 8-lane-group dwordx4 scheme; fp16 xw consumed via
// fmaf(v, half2float(h), acc) -> v_fma_mix_f32 (no extract instructions).
// ---------------------------------------------------------------------------
union U8 {
  uint4 u4;
  __half h[8];
};

__device__ __forceinline__ void edge_fma(float* a, const U8& u, float v) {
#pragma unroll
  for (int k = 0; k < 8; ++k)
    a[k] = fmaf(v, __half2float(u.h[k]), a[k]);
}

__global__ __launch_bounds__(256) void gather_kernel(
    const unsigned int* __restrict__ rowinfo, const int2* __restrict__ ebuf,
    const char* __restrict__ xwbytes, float4* __restrict__ outf4,
    const int* __restrict__ spillcnt, const int4* __restrict__ spill,
    int n) {
  const int lane = threadIdx.x & 63;
  const int g = lane >> 3;        // edge slot 0..7
  const int l8 = lane & 7;        // channel-quad index
  const int l8b = l8 << 4;        // byte offset within row
  const int w = (blockIdx.x * blockDim.x + threadIdx.x) >> 6;
  const int nw = (gridDim.x * blockDim.x) >> 6;
  const int sc = min(*spillcnt, SPILLMAX);

  for (int row = w; row < n; row += nw) {
    const float4 lin0 = outf4[(size_t)row * 16 + 2 * l8];
    const float4 lin1 = outf4[(size_t)row * 16 + 2 * l8 + 1];

    float a[8];
#pragma unroll
    for (int k = 0; k < 8; ++k) a[k] = 0.f;

    const unsigned int info = rowinfo[row];
    const int beg = (row >> RPB_SH) * CAPG + (int)(info >> 16);
    const int end = beg + (int)(info & 0xFFFFu);

    int e = beg;
    for (; e + 16 <= end; e += 16) {
      const int2 rc0 = ebuf[e + g];
      const int2 rc1 = ebuf[e + 8 + g];
      U8 u0, u1;
      u0.u4 = *(const uint4*)(xwbytes + (rc0.x & COLOFF_MASK) + l8b);
      u1.u4 = *(const uint4*)(xwbytes + (rc1.x & COLOFF_MASK) + l8b);
      edge_fma(a, u0, __int_as_float(rc0.y));
      edge_fma(a, u1, __int_as_float(rc1.y));
    }
    for (; e < end; e += 8) {
      const int idx = e + g;
      const bool ok = idx < end;
      const int2 rc = ebuf[ok ? idx : (end - 1)];
      U8 u;
      u.u4 = *(const uint4*)(xwbytes + (rc.x & COLOFF_MASK) + l8b);
      edge_fma(a, u, ok ? __int_as_float(rc.y) : 0.f);
    }

    if (sc > 0) {  // spill pass (empty in practice; uniform branch)
      for (int s = 0; s < sc; ++s) {
        const int4 r = spill[s];
        if (r.x == row && g == 0) {
          U8 u;
          u.u4 = *(const uint4*)(xwbytes + r.y + l8b);
          edge_fma(a, u, __int_as_float(r.z));
        }
      }
    }

    // butterfly merge across the 8 groups
#pragma unroll
    for (int k = 0; k < 8; ++k) {
      a[k] += __shfl_xor(a[k], 8, 64);
      a[k] += __shfl_xor(a[k], 16, 64);
      a[k] += __shfl_xor(a[k], 32, 64);
    }

    if (lane < 8) {  // g == 0: l8 = lane
      float4 o0, o1;
      o0.x = 1.f / (1.f + __expf(-(lin0.x + a[0])));
      o0.y = 1.f / (1.f + __expf(-(lin0.y + a[1])));
      o0.z = 1.f / (1.f + __expf(-(lin0.z + a[2])));
      o0.w = 1.f / (1.f + __expf(-(lin0.w + a[3])));
      o1.x = 1.f / (1.f + __expf(-(lin1.x + a[4])));
      o1.y = 1.f / (1.f + __expf(-(lin1.y + a[5])));
      o1.z = 1.f / (1.f + __expf(-(lin1.z + a[6])));
      o1.w = 1.f / (1.f + __expf(-(lin1.w + a[7])));
      outf4[(size_t)row * 16 + 2 * l8] = o0;
      outf4[(size_t)row * 16 + 2 * l8 + 1] = o1;
    }
  }
}

// ---------------------------------------------------------------------------
// Fallback path (ws too small): atomic scatter + sigmoid.
// ---------------------------------------------------------------------------
__global__ __launch_bounds__(256) void scatter_kernel(
    const int* __restrict__ rows, const int* __restrict__ cols,
    const float* __restrict__ vals, const __half* __restrict__ xwh,
    float* __restrict__ out, int nnz) {
  const int lane = threadIdx.x & 63;
  const int wid = (blockIdx.x * blockDim.x + threadIdx.x) >> 6;
  const int nwaves = (gridDim.x * blockDim.x) >> 6;
  for (int k = wid; k < nnz; k += nwaves) {
    const float xv = __half2float(xwh[(size_t)cols[k] * CH + lane]);
    atomicAdd(&out[(size_t)rows[k] * CH + lane], vals[k] * xv);
  }
}

__global__ __launch_bounds__(256) void sigmoid_kernel(float* __restrict__ out, int n4) {
  const int i = blockIdx.x * blockDim.x + threadIdx.x;
  if (i < n4) {
    float4 v = reinterpret_cast<float4*>(out)[i];
    v.x = 1.f / (1.f + __expf(-v.x));
    v.y = 1.f / (1.f + __expf(-v.y));
    v.z = 1.f / (1.f + __expf(-v.z));
    v.w = 1.f / (1.f + __expf(-v.w));
    reinterpret_cast<float4*>(out)[i] = v;
  }
}

extern "C" void kernel_launch(void* const* d_in, const int* in_sizes, int n_in,
                              void* d_out, int out_size, void* d_ws, size_t ws_size,
                              hipStream_t stream) {
  const float* x         = (const float*)d_in[0];
  const int*   down_rows = (const int*)d_in[1];
  const int*   down_cols = (const int*)d_in[2];
  const float* down_vals = (const float*)d_in[3];
  const int*   up_rows   = (const int*)d_in[4];
  const int*   up_cols   = (const int*)d_in[5];
  const float* up_vals   = (const float*)d_in[6];
  const float* w_conv    = (const float*)d_in[7];
  const float* w_lin     = (const float*)d_in[8];

  const int n   = in_sizes[0] / CH;  // 100000
  const int nnz = in_sizes[1];       // 1600000
  const int nb  = (n + RPB - 1) / RPB;  // 782

  float* out = (float*)d_out;

  // ws layout (xw stored as fp16)
  char* p = (char*)d_ws;
  __half* xwh  = (__half*)p;  p += (size_t)n * CH * 2;
  int* gcur    = (int*)p;  p += (size_t)nb * 4;
  int* spillc  = (int*)p;  p += 16;           // spill counter (+pad)
  unsigned int* rowinfo = (unsigned int*)p;  p += ((size_t)n + 2) * 4;
  p = (char*)(((uintptr_t)p + 15) & ~(uintptr_t)15);
  int4* spill  = (int4*)p; p += (size_t)SPILLMAX * 16;
  int2* ebuf   = (int2*)p; p += (size_t)nb * CAPG * 8;
  const size_t need = (size_t)(p - (char*)d_ws);

  if (ws_size >= need && nb <= MAXNB && n < (1 << 17)) {
    hipMemsetAsync(gcur, 0, (size_t)nb * 4 + 16, stream);  // gcur + spillc
    gemm_kernel<<<GEMM_BLOCKS, 256, 0, stream>>>(x, w_conv, w_lin, xwh, out, n);
    fillR_kernel<<<FILL_BLOCKS, 1024, 0, stream>>>(
        down_rows, down_cols, down_vals, up_rows, up_cols, up_vals,
        gcur, spillc, spill, ebuf, nnz, nb);
    sortB_kernel<<<nb, 512, 0, stream>>>(gcur, ebuf, rowinfo, n, nb);
    const int nblk = (n + 3) / 4;
    gather_kernel<<<nblk, 256, 0, stream>>>(rowinfo, ebuf, (const char*)xwh,
                                            (float4*)out, spillc, spill, n);
  } else {
    gemm_kernel<<<GEMM_BLOCKS, 256, 0, stream>>>(x, w_conv, w_lin, xwh, out, n);
    scatter_kernel<<<4096, 256, 0, stream>>>(down_rows, down_cols, down_vals, xwh, out, nnz);
    scatter_kernel<<<4096, 256, 0, stream>>>(up_rows, up_cols, up_vals, xwh, out, nnz);
    const int n4 = (n * CH) / 4;
    sigmoid_kernel<<<(n4 + 255) / 256, 256, 0, stream>>>(out, n4);
  }
}